// Round 1
// baseline (245.704 us; speedup 1.0000x reference)
//
#include <hip/hip_runtime.h>

#define NUM_E   2048
#define DIM     64
#define NROWS   32768            // 32*32*32
#define NELEM   2097152          // NROWS*DIM

// numpy pairwise_sum for n=64 of squares: 8 accumulators + tree combine.
// contract(off) so products round to f32 before the adds (matches np: flat*flat
// materialized, then summed).
__device__ __forceinline__ float np_sumsq64(const float* z) {
#pragma clang fp contract(off)
    float r[8];
    #pragma unroll
    for (int j = 0; j < 8; ++j) r[j] = z[j] * z[j];
    #pragma unroll
    for (int i = 8; i < 64; i += 8) {
        #pragma unroll
        for (int j = 0; j < 8; ++j) r[j] += z[i + j] * z[i + j];
    }
    return ((r[0] + r[1]) + (r[2] + r[3])) + ((r[4] + r[5]) + (r[6] + r[7]));
}

// per-code ||e||^2, numpy-bitwise
__global__ void se_kernel(const float* __restrict__ cb, float* __restrict__ se) {
    int k = blockIdx.x * blockDim.x + threadIdx.x;
    if (k < NUM_E) {
        float z[DIM];
        #pragma unroll
        for (int d = 0; d < DIM; ++d) z[d] = cb[(size_t)k * DIM + d];
        se[k] = np_sumsq64(z);
    }
}

// block: 1024 threads = 16 waves; 64 rows per block; wave w scans codes
// [w*128, w*128+128) for all 64 rows (one row per lane, z in VGPRs).
__global__ __launch_bounds__(1024, 4) void vq_main(
        const float* __restrict__ x, const float* __restrict__ cb,
        const float* __restrict__ se, float* __restrict__ out_q,
        float* __restrict__ out_idx, float* __restrict__ loss_accum,
        unsigned int* __restrict__ counts) {
    __shared__ float xs[64 * 65];          // padded stride 65: conflict-free
    __shared__ float red_d[16 * 64];
    __shared__ int   red_i[16 * 64];
    __shared__ int   ids[64];
    __shared__ float lred[16];

    const int t    = threadIdx.x;
    const int lane = t & 63;
    const int w    = t >> 6;
    const int brow = blockIdx.x * 64;

    // stage x tile (64 rows x 64) coalesced
    #pragma unroll
    for (int i = 0; i < 4; ++i) {
        int lin = i * 1024 + t;
        int r = lin >> 6, d = lin & 63;
        xs[r * 65 + d] = x[(size_t)brow * DIM + lin];
    }
    __syncthreads();

    // this lane's row into registers
    float z[DIM];
    #pragma unroll
    for (int d = 0; d < DIM; ++d) z[d] = xs[lane * 65 + d];

    const float sz = np_sumsq64(z);

    // wave-uniform code chunk -> scalar loads for cb/se
    const int c0 = __builtin_amdgcn_readfirstlane(w) * 128;

    float best = 3.4e38f;
    int   bidx = 0;
    #pragma unroll 2
    for (int c = 0; c < 128; ++c) {
        const int k = c0 + c;
        const float* e = cb + (size_t)k * DIM;
        float dot = 0.0f;                  // sequential chain ~ BLAS microkernel
        #pragma unroll
        for (int d = 0; d < DIM; ++d) dot = fmaf(z[d], e[d], dot);
        float dist;
        {
#pragma clang fp contract(off)
            float t1 = sz + se[k];         // same op order as reference
            dist = t1 - 2.0f * dot;
        }
        if (dist < best) { best = dist; bidx = k; }   // strict <: first-index ties
    }
    red_d[w * 64 + lane] = best;
    red_i[w * 64 + lane] = bidx;
    __syncthreads();

    // wave 0 reduces 16 chunks per row (ascending chunk = ascending code index)
    if (t < 64) {
        float bd = red_d[t];
        int   bi = red_i[t];
        #pragma unroll
        for (int w2 = 1; w2 < 16; ++w2) {
            float d2 = red_d[w2 * 64 + t];
            if (d2 < bd) { bd = d2; bi = red_i[w2 * 64 + t]; }
        }
        ids[t] = bi;
        out_idx[brow + t] = (float)bi;
        atomicAdd(&counts[bi], 1u);
    }
    __syncthreads();

    // quantized_st = x + (q - x), written with the reference's exact rounding;
    // loss accumulated per block
    float lsum = 0.0f;
    #pragma unroll
    for (int i = 0; i < 4; ++i) {
        int lin = i * 1024 + t;
        int r = lin >> 6, d = lin & 63;
        float q  = cb[(size_t)ids[r] * DIM + d];
        float xv = xs[r * 65 + d];
        float outv;
        {
#pragma clang fp contract(off)
            outv = xv + (q - xv);
        }
        out_q[(size_t)brow * DIM + lin] = outv;
        float diff = xv - q;
        lsum = fmaf(diff, diff, lsum);
    }
    #pragma unroll
    for (int off = 32; off; off >>= 1) lsum += __shfl_down(lsum, off, 64);
    if (lane == 0) lred[w] = lsum;
    __syncthreads();
    if (t == 0) {
        float s = 0.0f;
        #pragma unroll
        for (int i = 0; i < 16; ++i) s += lred[i];
        atomicAdd(loss_accum, s);
    }
}

__global__ void finalize(const unsigned int* __restrict__ counts,
                         const float* __restrict__ loss_accum,
                         float* __restrict__ out_scalars) {
    __shared__ float partial[256];
    int t = threadIdx.x;
    float s = 0.0f;
    for (int i = t; i < NUM_E; i += 256) {
        float p = (float)counts[i] * (1.0f / 32768.0f);
        s += p * logf(p + 1e-10f);
    }
    partial[t] = s;
    __syncthreads();
    for (int off = 128; off; off >>= 1) {
        if (t < off) partial[t] += partial[t + off];
        __syncthreads();
    }
    if (t == 0) {
        float loss = *loss_accum * (1.0f / (float)NELEM);
        out_scalars[0] = loss;            // vq_loss
        out_scalars[1] = loss;            // commit_loss (identical by source)
        out_scalars[2] = expf(-partial[0]);  // perplexity
    }
}

extern "C" void kernel_launch(void* const* d_in, const int* in_sizes, int n_in,
                              void* d_out, int out_size, void* d_ws, size_t ws_size,
                              hipStream_t stream) {
    const float* x  = (const float*)d_in[0];
    const float* cb = (const float*)d_in[1];

    float* out_q       = (float*)d_out;               // [0, 2097152)
    float* out_scalars = (float*)d_out + NELEM;       // vq, commit, perplexity
    float* out_idx     = (float*)d_out + NELEM + 3;   // 32768 indices as f32

    unsigned int* counts   = (unsigned int*)d_ws;                       // 8 KB
    float*        loss_acc = (float*)((char*)d_ws + 8192);              // 4 B
    float*        se       = (float*)((char*)d_ws + 8448);              // 8 KB

    hipMemsetAsync(d_ws, 0, 8448, stream);
    se_kernel<<<dim3(8), dim3(256), 0, stream>>>(cb, se);
    vq_main<<<dim3(512), dim3(1024), 0, stream>>>(x, cb, se, out_q, out_idx,
                                                  loss_acc, counts);
    finalize<<<dim3(1), dim3(256), 0, stream>>>(counts, loss_acc, out_scalars);
}

// Round 3
// 245.444 us; speedup vs baseline: 1.0011x; 1.0011x over previous
//
#include <hip/hip_runtime.h>

#define NUM_E   2048
#define DIM     64
#define NROWS   32768            // 32*32*32
#define NELEM   2097152          // NROWS*DIM

// numpy pairwise_sum for n=64 of squares: 8 accumulators + tree combine.
// contract(off) so products round to f32 before the adds (matches np: flat*flat
// materialized, then summed).
__device__ __forceinline__ float np_sumsq64(const float* z) {
#pragma clang fp contract(off)
    float r[8];
    #pragma unroll
    for (int j = 0; j < 8; ++j) r[j] = z[j] * z[j];
    #pragma unroll
    for (int i = 8; i < 64; i += 8) {
        #pragma unroll
        for (int j = 0; j < 8; ++j) r[j] += z[i + j] * z[i + j];
    }
    return ((r[0] + r[1]) + (r[2] + r[3])) + ((r[4] + r[5]) + (r[6] + r[7]));
}

// per-code ||e||^2, numpy-bitwise
__global__ void se_kernel(const float* __restrict__ cb, float* __restrict__ se) {
    int k = blockIdx.x * blockDim.x + threadIdx.x;
    if (k < NUM_E) {
        float z[DIM];
        #pragma unroll
        for (int d = 0; d < DIM; ++d) z[d] = cb[(size_t)k * DIM + d];
        se[k] = np_sumsq64(z);
    }
}

// block: 1024 threads = 16 waves; 64 rows per block; wave w scans codes
// [w*128, w*128+128) for all 64 rows (one row per lane, z in VGPRs).
// launch_bounds (1024,2): 256-VGPR budget so z[64] never spills in the loop.
__global__ __launch_bounds__(1024, 2) void vq_main(
        const float* __restrict__ x, const float* __restrict__ cb,
        const float* __restrict__ se, float* __restrict__ out_q,
        float* __restrict__ out_idx, float* __restrict__ loss_accum,
        unsigned int* __restrict__ counts) {
    __shared__ float xs[64 * 65];          // padded stride 65: conflict-free
    __shared__ float red_d[16 * 64];
    __shared__ int   red_i[16 * 64];
    __shared__ int   ids[64];
    __shared__ float lred[16];

    const int t    = threadIdx.x;
    const int lane = t & 63;
    const int w    = t >> 6;
    const int brow = blockIdx.x * 64;

    // stage x tile (64 rows x 64) coalesced
    #pragma unroll
    for (int i = 0; i < 4; ++i) {
        int lin = i * 1024 + t;
        int r = lin >> 6, d = lin & 63;
        xs[r * 65 + d] = x[(size_t)brow * DIM + lin];
    }
    __syncthreads();

    // this lane's row into registers
    float z[DIM];
    #pragma unroll
    for (int d = 0; d < DIM; ++d) z[d] = xs[lane * 65 + d];

    const float sz = np_sumsq64(z);

    // Fence: MachineSink may not move the ds_reads of z past a barrier (other
    // threads could legally write xs after it). This pins z in VGPRs instead
    // of letting the compiler re-read LDS 128x inside the scan loop (which
    // made round-1 LDS-BW-bound: 17 GB LDS traffic ~ 250us).
    __syncthreads();

    // wave-uniform code chunk -> scalar (s_load) path for cb/se
    const int c0 = __builtin_amdgcn_readfirstlane(w) * 128;

    float best = 3.4e38f;
    int   bidx = 0;
    #pragma unroll 2
    for (int c = 0; c < 128; ++c) {
        const int k = c0 + c;
        const float* e = cb + (size_t)k * DIM;
        float dot = 0.0f;                  // sequential chain ~ BLAS microkernel
        #pragma unroll
        for (int d = 0; d < DIM; ++d) dot = fmaf(z[d], e[d], dot);
        float dist;
        {
#pragma clang fp contract(off)
            float t1 = sz + se[k];         // same op order as reference
            dist = t1 - 2.0f * dot;
        }
        if (dist < best) { best = dist; bidx = k; }   // strict <: first-index ties
    }
    red_d[w * 64 + lane] = best;
    red_i[w * 64 + lane] = bidx;
    __syncthreads();

    // wave 0 reduces 16 chunks per row (ascending chunk = ascending code index)
    if (t < 64) {
        float bd = red_d[t];
        int   bi = red_i[t];
        #pragma unroll
        for (int w2 = 1; w2 < 16; ++w2) {
            float d2 = red_d[w2 * 64 + t];
            if (d2 < bd) { bd = d2; bi = red_i[w2 * 64 + t]; }
        }
        ids[t] = bi;
        out_idx[brow + t] = (float)bi;
        atomicAdd(&counts[bi], 1u);
    }
    __syncthreads();

    // quantized_st = x + (q - x), written with the reference's exact rounding;
    // loss accumulated per block
    float lsum = 0.0f;
    #pragma unroll
    for (int i = 0; i < 4; ++i) {
        int lin = i * 1024 + t;
        int r = lin >> 6, d = lin & 63;
        float q  = cb[(size_t)ids[r] * DIM + d];
        float xv = xs[r * 65 + d];
        float outv;
        {
#pragma clang fp contract(off)
            outv = xv + (q - xv);
        }
        out_q[(size_t)brow * DIM + lin] = outv;
        float diff = xv - q;
        lsum = fmaf(diff, diff, lsum);
    }
    #pragma unroll
    for (int off = 32; off; off >>= 1) lsum += __shfl_down(lsum, off, 64);
    if (lane == 0) lred[w] = lsum;
    __syncthreads();
    if (t == 0) {
        float s = 0.0f;
        #pragma unroll
        for (int i = 0; i < 16; ++i) s += lred[i];
        atomicAdd(loss_accum, s);
    }
}

__global__ void finalize(const unsigned int* __restrict__ counts,
                         const float* __restrict__ loss_accum,
                         float* __restrict__ out_scalars) {
    __shared__ float partial[256];
    int t = threadIdx.x;
    float s = 0.0f;
    for (int i = t; i < NUM_E; i += 256) {
        float p = (float)counts[i] * (1.0f / 32768.0f);
        s += p * logf(p + 1e-10f);
    }
    partial[t] = s;
    __syncthreads();
    for (int off = 128; off; off >>= 1) {
        if (t < off) partial[t] += partial[t + off];
        __syncthreads();
    }
    if (t == 0) {
        float loss = *loss_accum * (1.0f / (float)NELEM);
        out_scalars[0] = loss;            // vq_loss
        out_scalars[1] = loss;            // commit_loss (identical by source)
        out_scalars[2] = expf(-partial[0]);  // perplexity
    }
}

extern "C" void kernel_launch(void* const* d_in, const int* in_sizes, int n_in,
                              void* d_out, int out_size, void* d_ws, size_t ws_size,
                              hipStream_t stream) {
    const float* x  = (const float*)d_in[0];
    const float* cb = (const float*)d_in[1];

    float* out_q       = (float*)d_out;               // [0, 2097152)
    float* out_scalars = (float*)d_out + NELEM;       // vq, commit, perplexity
    float* out_idx     = (float*)d_out + NELEM + 3;   // 32768 indices as f32

    unsigned int* counts   = (unsigned int*)d_ws;                       // 8 KB
    float*        loss_acc = (float*)((char*)d_ws + 8192);              // 4 B
    float*        se       = (float*)((char*)d_ws + 8448);              // 8 KB

    hipMemsetAsync(d_ws, 0, 8448, stream);
    se_kernel<<<dim3(8), dim3(256), 0, stream>>>(cb, se);
    vq_main<<<dim3(512), dim3(1024), 0, stream>>>(x, cb, se, out_q, out_idx,
                                                  loss_acc, counts);
    finalize<<<dim3(1), dim3(256), 0, stream>>>(counts, loss_acc, out_scalars);
}